// Round 5
// baseline (25.657 us; speedup 1.0000x reference)
//
#include <hip/hip_runtime.h>
#include <hip/hip_bf16.h>
#include <math.h>

#define EMBED 64
#define TB 8           // batch elements per block
#define BATCH 16384
#define LDX 136        // bf16 elems per LDS row (272B stride, conflict-free b128)

typedef __attribute__((ext_vector_type(8))) short short8;  // bf16x8 MFMA A/B frag
typedef __attribute__((ext_vector_type(4))) float f32x4;   // MFMA C/D frag

// ---- pre-pass: convert W1 (16384) and W2 (8192) to bf16 in workspace ----
__global__ __launch_bounds__(256) void cvt_weights(const float* __restrict__ W1,
                                                   const float* __restrict__ W2,
                                                   __hip_bfloat16* __restrict__ Wb) {
    const int i = blockIdx.x * 256 + threadIdx.x;   // 24576 threads
    if (i < 16384)      Wb[i] = __float2bfloat16(W1[i]);
    else if (i < 24576) Wb[i] = __float2bfloat16(W2[i - 16384]);
}

__global__ __launch_bounds__(256, 8) void ncf_fused(
    const int* __restrict__ user, const int* __restrict__ item,
    const int* __restrict__ p1, const int* __restrict__ p2,
    const int* __restrict__ p3, const int* __restrict__ p4, const int* __restrict__ p5,
    const float* __restrict__ Wu, const float* __restrict__ bu,
    const float* __restrict__ Wi, const float* __restrict__ bi,
    const float* __restrict__ b1v, const float* __restrict__ b2v,
    const float* __restrict__ W3, const float* __restrict__ b3,
    const __hip_bfloat16* __restrict__ W1b, const __hip_bfloat16* __restrict__ W2b,
    float* __restrict__ out)
{
    // LDS arrays keep 16 rows (MFMA tile height); batch rows 0..TB-1 are live.
    __shared__ __align__(16) __hip_bfloat16 xs [16 * LDX];
    __shared__ __align__(16) __hip_bfloat16 h1s[16 * LDX];
    __shared__ __align__(16) float          h2s[16 * 68];

    const int t    = threadIdx.x;
    const int lane = t & 63;
    const int wv   = t >> 6;       // 0..3
    const int blk  = blockIdx.x;

    const int fr = lane & 15;      // MFMA: A row / B col / C col
    const int kg = lane >> 4;      // MFMA: k-group 0..3

    // ---------------- Phase 1: embeddings + attention (fp32) ----------------
    const float bu_l = bu[lane];
    const float bi_l = bi[lane];

    #pragma unroll
    for (int e = 0; e < TB / 4; ++e) {          // 2 batch elements per wave
        const int b  = wv * (TB / 4) + e;
        const int gb = blk * TB + b;

        const int iu = user[gb];
        const int ii = item[gb];
        int ip[5];
        ip[0] = p1[gb]; ip[1] = p2[gb]; ip[2] = p3[gb]; ip[3] = p4[gb]; ip[4] = p5[gb];

        const float eu = fmaxf(Wu[(size_t)iu * EMBED + lane] + bu_l, 0.0f);
        const float ei = fmaxf(Wi[(size_t)ii * EMBED + lane] + bi_l, 0.0f);

        float ep[5], w[5];
        #pragma unroll
        for (int k = 0; k < 5; ++k) {
            ep[k] = fmaxf(Wi[(size_t)ip[k] * EMBED + lane] + bi_l, 0.0f);
            w[k]  = ei * ep[k];
        }

        #pragma unroll
        for (int k = 0; k < 5; ++k) {
            float v = w[k];
            #pragma unroll
            for (int off = 32; off >= 1; off >>= 1)
                v += __shfl_xor(v, off, 64);
            w[k] = v;
        }

        float m = w[0];
        #pragma unroll
        for (int k = 1; k < 5; ++k) m = fmaxf(m, w[k]);
        float z[5], s = 0.0f;
        #pragma unroll
        for (int k = 0; k < 5; ++k) { z[k] = expf(w[k] - m); s += z[k]; }
        const float inv_s = 1.0f / s;

        float pum = 0.0f;
        #pragma unroll
        for (int k = 0; k < 5; ++k) pum += z[k] * ep[k];
        pum *= inv_s;

        const float pu = eu + 0.2f * pum;
        xs[b * LDX + lane]      = __float2bfloat16(pu);
        xs[b * LDX + 64 + lane] = __float2bfloat16(ei);

        // zero the unused MFMA rows (8..15) so no garbage enters the matrix path
        xs[(TB + b) * LDX + lane]      = __float2bfloat16(0.0f);
        xs[(TB + b) * LDX + 64 + lane] = __float2bfloat16(0.0f);
    }

    __syncthreads();

    // ---------------- Layer 1: h1 = relu(X @ W1^T + b1), MFMA ----------------
    // A-frags hoisted once; two sequential 16-col tiles keep live B-frags at 4.
    const int n0 = wv * 32;
    {
        short8 a[4];
        #pragma unroll
        for (int kc = 0; kc < 4; ++kc)
            a[kc] = *reinterpret_cast<const short8*>(&xs[fr * LDX + kc * 32 + kg * 8]);

        #pragma unroll
        for (int tile = 0; tile < 2; ++tile) {
            const int nc = n0 + tile * 16;
            short8 bf[4];
            #pragma unroll
            for (int kc = 0; kc < 4; ++kc)
                bf[kc] = *reinterpret_cast<const short8*>(
                    &W1b[(nc + fr) * 128 + kc * 32 + kg * 8]);

            const float bb = b1v[nc + fr];
            f32x4 c = {bb, bb, bb, bb};
            #pragma unroll
            for (int kc = 0; kc < 4; ++kc)
                c = __builtin_amdgcn_mfma_f32_16x16x32_bf16(a[kc], bf[kc], c, 0, 0, 0);

            #pragma unroll
            for (int r = 0; r < 4; ++r)
                h1s[(kg * 4 + r) * LDX + nc + fr] = __float2bfloat16(fmaxf(c[r], 0.0f));
        }
    }

    __syncthreads();

    // ---------------- Layer 2: h2 = relu(H1 @ W2^T + b2), MFMA ----------------
    const int n2 = wv * 16;
    {
        short8 a2[4], b2f[4];
        #pragma unroll
        for (int kc = 0; kc < 4; ++kc) {
            a2[kc]  = *reinterpret_cast<const short8*>(&h1s[fr * LDX + kc * 32 + kg * 8]);
            b2f[kc] = *reinterpret_cast<const short8*>(
                &W2b[(n2 + fr) * 128 + kc * 32 + kg * 8]);
        }

        const float bb2 = b2v[n2 + fr];
        f32x4 c2 = {bb2, bb2, bb2, bb2};
        #pragma unroll
        for (int kc = 0; kc < 4; ++kc)
            c2 = __builtin_amdgcn_mfma_f32_16x16x32_bf16(a2[kc], b2f[kc], c2, 0, 0, 0);

        #pragma unroll
        for (int r = 0; r < 4; ++r)
            h2s[(kg * 4 + r) * 68 + n2 + fr] = fmaxf(c2[r], 0.0f);
    }

    __syncthreads();

    // ---------------- Layer 3 + sigmoid (wave 0, batch rows 0..TB-1) ----------------
    if (wv == 0) {
        const int b = lane >> 2;       // 0..15, only b<TB stored
        const int q = lane & 3;        // k-quarter
        const float4* w3p = reinterpret_cast<const float4*>(&W3[q * 16]);
        const float4* hp  = reinterpret_cast<const float4*>(&h2s[b * 68 + q * 16]);
        float acc = 0.0f;
        #pragma unroll
        for (int j = 0; j < 4; ++j) {
            const float4 w = w3p[j];
            const float4 h = hp[j];
            acc += h.x * w.x + h.y * w.y + h.z * w.z + h.w * w.w;
        }
        acc += __shfl_xor(acc, 1, 64);
        acc += __shfl_xor(acc, 2, 64);
        if (q == 0 && b < TB)
            out[blk * TB + b] = 1.0f / (1.0f + expf(-(acc + b3[0])));
    }
}

extern "C" void kernel_launch(void* const* d_in, const int* in_sizes, int n_in,
                              void* d_out, int out_size, void* d_ws, size_t ws_size,
                              hipStream_t stream) {
    const int*   user = (const int*)  d_in[0];
    const int*   item = (const int*)  d_in[1];
    const int*   p1   = (const int*)  d_in[2];
    const int*   p2   = (const int*)  d_in[3];
    const int*   p3   = (const int*)  d_in[4];
    const int*   p4   = (const int*)  d_in[5];
    const int*   p5   = (const int*)  d_in[6];
    const float* Wu   = (const float*)d_in[7];
    const float* bu   = (const float*)d_in[8];
    const float* Wi   = (const float*)d_in[9];
    const float* bi   = (const float*)d_in[10];
    const float* W1   = (const float*)d_in[11];
    const float* b1   = (const float*)d_in[12];
    const float* W2   = (const float*)d_in[13];
    const float* b2   = (const float*)d_in[14];
    const float* W3   = (const float*)d_in[15];
    const float* b3   = (const float*)d_in[16];
    float* out = (float*)d_out;

    __hip_bfloat16* W1b = (__hip_bfloat16*)d_ws;          // 16384 elems
    __hip_bfloat16* W2b = W1b + 16384;                    // 8192 elems

    hipLaunchKernelGGL(cvt_weights, dim3(96), dim3(256), 0, stream, W1, W2, W1b);

    hipLaunchKernelGGL(ncf_fused, dim3(BATCH / TB), dim3(256), 0, stream,
                       user, item, p1, p2, p3, p4, p5,
                       Wu, bu, Wi, bi, b1, b2, W3, b3, W1b, W2b, out);
}

// Round 6
// 19.553 us; speedup vs baseline: 1.3122x; 1.3122x over previous
//
#include <hip/hip_runtime.h>
#include <hip/hip_bf16.h>
#include <math.h>

#define EMBED 64
#define TB 16          // batch elements per block
#define BATCH 16384
#define LDX 136        // bf16 elems per LDS row (272B stride)

typedef __attribute__((ext_vector_type(8))) short short8;  // bf16x8 MFMA A/B frag
typedef __attribute__((ext_vector_type(4))) float f32x4;   // MFMA C/D frag

__device__ inline void store_bf16x4(__hip_bfloat16* dst, float4 v) {
    __hip_bfloat16 tmp[4];
    tmp[0] = __float2bfloat16(v.x); tmp[1] = __float2bfloat16(v.y);
    tmp[2] = __float2bfloat16(v.z); tmp[3] = __float2bfloat16(v.w);
    *reinterpret_cast<ushort4*>(dst) = *reinterpret_cast<ushort4*>(tmp);
}

__device__ inline short8 load_w_bf16(const float* p) {
    const float4 lo = reinterpret_cast<const float4*>(p)[0];
    const float4 hi = reinterpret_cast<const float4*>(p)[1];
    __hip_bfloat16 tb[8];
    tb[0] = __float2bfloat16(lo.x); tb[1] = __float2bfloat16(lo.y);
    tb[2] = __float2bfloat16(lo.z); tb[3] = __float2bfloat16(lo.w);
    tb[4] = __float2bfloat16(hi.x); tb[5] = __float2bfloat16(hi.y);
    tb[6] = __float2bfloat16(hi.z); tb[7] = __float2bfloat16(hi.w);
    return *reinterpret_cast<short8*>(tb);
}

__global__ __launch_bounds__(256, 4) void ncf_fused(
    const int* __restrict__ user, const int* __restrict__ item,
    const int* __restrict__ p1, const int* __restrict__ p2,
    const int* __restrict__ p3, const int* __restrict__ p4, const int* __restrict__ p5,
    const float* __restrict__ Wu, const float* __restrict__ bu,
    const float* __restrict__ Wi, const float* __restrict__ bi,
    const float* __restrict__ W1, const float* __restrict__ b1v,
    const float* __restrict__ W2, const float* __restrict__ b2v,
    const float* __restrict__ W3, const float* __restrict__ b3,
    float* __restrict__ out)
{
    __shared__ __align__(16) __hip_bfloat16 xs [TB * LDX];
    __shared__ __align__(16) __hip_bfloat16 h1s[TB * LDX];
    __shared__ __align__(16) float          h2s[TB * 68];

    const int t    = threadIdx.x;
    const int lane = t & 63;
    const int wv   = t >> 6;       // 0..3
    const int blk  = blockIdx.x;

    const int fr = lane & 15;      // MFMA: A row / B col / C col
    const int kg = lane >> 4;      // MFMA: k-group 0..3

    // ---------------- Phase 1: embeddings + attention ----------------
    // Remap: 16 lanes x float4 per batch element; one wave = 4 elements at once.
    {
        const int sub = lane >> 4;         // element within wave group (0..3)
        const int el  = lane & 15;         // float4 position within E=64
        const int b   = wv * 4 + sub;      // 0..15
        const int gb  = blk * TB + b;

        const int iu = user[gb];
        const int ii = item[gb];
        int ip[5];
        ip[0] = p1[gb]; ip[1] = p2[gb]; ip[2] = p3[gb]; ip[3] = p4[gb]; ip[4] = p5[gb];

        const float4 bu4 = reinterpret_cast<const float4*>(bu)[el];
        const float4 bi4 = reinterpret_cast<const float4*>(bi)[el];

        // all 7 gathers issue in parallel (dwordx4 each)
        const float4 eu_r = reinterpret_cast<const float4*>(&Wu[(size_t)iu * EMBED])[el];
        const float4 ei_r = reinterpret_cast<const float4*>(&Wi[(size_t)ii * EMBED])[el];
        float4 ep[5];
        #pragma unroll
        for (int k = 0; k < 5; ++k)
            ep[k] = reinterpret_cast<const float4*>(&Wi[(size_t)ip[k] * EMBED])[el];

        float4 eu, ei;
        eu.x = fmaxf(eu_r.x + bu4.x, 0.0f); eu.y = fmaxf(eu_r.y + bu4.y, 0.0f);
        eu.z = fmaxf(eu_r.z + bu4.z, 0.0f); eu.w = fmaxf(eu_r.w + bu4.w, 0.0f);
        ei.x = fmaxf(ei_r.x + bi4.x, 0.0f); ei.y = fmaxf(ei_r.y + bi4.y, 0.0f);
        ei.z = fmaxf(ei_r.z + bi4.z, 0.0f); ei.w = fmaxf(ei_r.w + bi4.w, 0.0f);

        float w[5];
        #pragma unroll
        for (int k = 0; k < 5; ++k) {
            ep[k].x = fmaxf(ep[k].x + bi4.x, 0.0f);
            ep[k].y = fmaxf(ep[k].y + bi4.y, 0.0f);
            ep[k].z = fmaxf(ep[k].z + bi4.z, 0.0f);
            ep[k].w = fmaxf(ep[k].w + bi4.w, 0.0f);
            w[k] = ei.x * ep[k].x + ei.y * ep[k].y + ei.z * ep[k].z + ei.w * ep[k].w;
        }

        // reduce over the 16-lane group: 4 butterfly steps
        #pragma unroll
        for (int k = 0; k < 5; ++k) {
            float v = w[k];
            v += __shfl_xor(v, 1, 64);
            v += __shfl_xor(v, 2, 64);
            v += __shfl_xor(v, 4, 64);
            v += __shfl_xor(v, 8, 64);
            w[k] = v;
        }

        float m = w[0];
        #pragma unroll
        for (int k = 1; k < 5; ++k) m = fmaxf(m, w[k]);
        float z[5], s = 0.0f;
        #pragma unroll
        for (int k = 0; k < 5; ++k) { z[k] = expf(w[k] - m); s += z[k]; }
        const float scale = 0.2f / s;

        float4 pum = {0.0f, 0.0f, 0.0f, 0.0f};
        #pragma unroll
        for (int k = 0; k < 5; ++k) {
            pum.x += z[k] * ep[k].x; pum.y += z[k] * ep[k].y;
            pum.z += z[k] * ep[k].z; pum.w += z[k] * ep[k].w;
        }
        float4 pu;
        pu.x = eu.x + scale * pum.x; pu.y = eu.y + scale * pum.y;
        pu.z = eu.z + scale * pum.z; pu.w = eu.w + scale * pum.w;

        store_bf16x4(&xs[b * LDX + el * 4], pu);
        store_bf16x4(&xs[b * LDX + 64 + el * 4], ei);
    }

    __syncthreads();

    // ---------------- Layer 1: h1 = relu(X @ W1^T + b1), MFMA ----------------
    const int n0 = wv * 32;
    {
        short8 a[4];
        #pragma unroll
        for (int kc = 0; kc < 4; ++kc)
            a[kc] = *reinterpret_cast<const short8*>(&xs[fr * LDX + kc * 32 + kg * 8]);

        #pragma unroll
        for (int tile = 0; tile < 2; ++tile) {
            const int nc = n0 + tile * 16;
            short8 bf[4];
            #pragma unroll
            for (int kc = 0; kc < 4; ++kc)
                bf[kc] = load_w_bf16(&W1[(nc + fr) * 128 + kc * 32 + kg * 8]);

            const float bb = b1v[nc + fr];
            f32x4 c = {bb, bb, bb, bb};
            #pragma unroll
            for (int kc = 0; kc < 4; ++kc)
                c = __builtin_amdgcn_mfma_f32_16x16x32_bf16(a[kc], bf[kc], c, 0, 0, 0);

            #pragma unroll
            for (int r = 0; r < 4; ++r)
                h1s[(kg * 4 + r) * LDX + nc + fr] = __float2bfloat16(fmaxf(c[r], 0.0f));
        }
    }

    __syncthreads();

    // ---------------- Layer 2: h2 = relu(H1 @ W2^T + b2), MFMA ----------------
    const int n2 = wv * 16;
    {
        short8 a2[4], b2f[4];
        #pragma unroll
        for (int kc = 0; kc < 4; ++kc) {
            a2[kc]  = *reinterpret_cast<const short8*>(&h1s[fr * LDX + kc * 32 + kg * 8]);
            b2f[kc] = load_w_bf16(&W2[(n2 + fr) * 128 + kc * 32 + kg * 8]);
        }

        const float bb2 = b2v[n2 + fr];
        f32x4 c2 = {bb2, bb2, bb2, bb2};
        #pragma unroll
        for (int kc = 0; kc < 4; ++kc)
            c2 = __builtin_amdgcn_mfma_f32_16x16x32_bf16(a2[kc], b2f[kc], c2, 0, 0, 0);

        #pragma unroll
        for (int r = 0; r < 4; ++r)
            h2s[(kg * 4 + r) * 68 + n2 + fr] = fmaxf(c2[r], 0.0f);
    }

    __syncthreads();

    // ---------------- Layer 3 + sigmoid (wave 0) ----------------
    if (wv == 0) {
        const int b = lane >> 2;       // batch element 0..15
        const int q = lane & 3;        // k-quarter
        const float4* w3p = reinterpret_cast<const float4*>(&W3[q * 16]);
        const float4* hp  = reinterpret_cast<const float4*>(&h2s[b * 68 + q * 16]);
        float acc = 0.0f;
        #pragma unroll
        for (int j = 0; j < 4; ++j) {
            const float4 w = w3p[j];
            const float4 h = hp[j];
            acc += h.x * w.x + h.y * w.y + h.z * w.z + h.w * w.w;
        }
        acc += __shfl_xor(acc, 1, 64);
        acc += __shfl_xor(acc, 2, 64);
        if (q == 0)
            out[blk * TB + b] = 1.0f / (1.0f + expf(-(acc + b3[0])));
    }
}

extern "C" void kernel_launch(void* const* d_in, const int* in_sizes, int n_in,
                              void* d_out, int out_size, void* d_ws, size_t ws_size,
                              hipStream_t stream) {
    const int*   user = (const int*)  d_in[0];
    const int*   item = (const int*)  d_in[1];
    const int*   p1   = (const int*)  d_in[2];
    const int*   p2   = (const int*)  d_in[3];
    const int*   p3   = (const int*)  d_in[4];
    const int*   p4   = (const int*)  d_in[5];
    const int*   p5   = (const int*)  d_in[6];
    const float* Wu   = (const float*)d_in[7];
    const float* bu   = (const float*)d_in[8];
    const float* Wi   = (const float*)d_in[9];
    const float* bi   = (const float*)d_in[10];
    const float* W1   = (const float*)d_in[11];
    const float* b1   = (const float*)d_in[12];
    const float* W2   = (const float*)d_in[13];
    const float* b2   = (const float*)d_in[14];
    const float* W3   = (const float*)d_in[15];
    const float* b3   = (const float*)d_in[16];
    float* out = (float*)d_out;

    hipLaunchKernelGGL(ncf_fused, dim3(BATCH / TB), dim3(256), 0, stream,
                       user, item, p1, p2, p3, p4, p5,
                       Wu, bu, Wi, bi, W1, b1, W2, b2, W3, b3, out);
}